// Round 21
// baseline (397.037 us; speedup 1.0000x reference)
//
#include <hip/hip_runtime.h>
#include <stdint.h>

// ============================================================================
// LSTMDecoder fused — MI355X/gfx950 — R21: fused dual-source gate passes
//
// R20 = 277us frontier (R11 layout + setprio + direct-global OUTs). Residual
// is pass-start L2 latency at 2 waves/SIMD (register-file law). R21 fuses the
// Wih+Whh gate passes of stages 1/2 into gate_gemm_dual: 8 B-loads in flight
// per kc (2x MLP), half the pass-start stalls, one prio region. Live set
// ~120-126 regs — tight under the 128 cap; spill signature = WRITE > 30MB.
// ============================================================================

typedef __attribute__((ext_vector_type(8))) short bf16x8;
typedef __attribute__((ext_vector_type(4))) float f32x4;

#define OFF_WIH  0
#define OFF_WHH  786432
#define OFF_HS   1310720
#define OFF_CS   1376256
#define OFF_MID  1441792
#define OFF_OUT0 1638400
#define OFF_OUT1 1654784
#define OFF_OUT2 1662976
#define PK_TOTAL 1671168

__device__ __forceinline__ unsigned short f2bf(float f){
  uint32_t u = __float_as_uint(f);
  u += 0x7FFFu + ((u >> 16) & 1u);
  return (unsigned short)(u >> 16);
}
__device__ __forceinline__ float bf2f(unsigned short h){
  return __uint_as_float(((uint32_t)h) << 16);
}
__device__ __forceinline__ float sigm(float x){
  return __builtin_amdgcn_rcpf(1.0f + __expf(-x));
}
__device__ __forceinline__ float tanh_(float x){
  return 2.0f * __builtin_amdgcn_rcpf(1.0f + __expf(-2.0f * x)) - 1.0f;
}

// ---------------------------------------------------------------------------
__global__ __launch_bounds__(256)
void pack_all(const float* __restrict__ Wih, const float* __restrict__ Whh,
              const float* __restrict__ hsW, const float* __restrict__ csW,
              const float* __restrict__ midW,
              const float* __restrict__ oW0, const float* __restrict__ oW1,
              const float* __restrict__ oW2,
              unsigned short* __restrict__ pk)
{
  int g = blockIdx.x * 256 + threadIdx.x;
  if (g >= PK_TOTAL / 8) return;
  int tile = g >> 9;
  int within = g & 511;
  int lane = within & 63;
  int kc = within >> 6;

  const float* s; int nt_local, Nsrc;
  if      (tile < 192){ int a = tile / 64; nt_local = tile % 64; s = Wih + (size_t)a * 262144; Nsrc = 1024; }
  else if (tile < 320){ int a = 1 + (tile - 192) / 64; nt_local = (tile - 192) % 64; s = Whh + (size_t)a * 262144; Nsrc = 1024; }
  else if (tile < 336){ nt_local = tile - 320; s = hsW; Nsrc = 256; }
  else if (tile < 352){ nt_local = tile - 336; s = csW; Nsrc = 256; }
  else if (tile < 400){ int a = (tile - 352) / 16; nt_local = (tile - 352) % 16; s = midW + a * 65536; Nsrc = 256; }
  else if (tile < 404){ nt_local = tile - 400; s = oW0; Nsrc = 54; }
  else if (tile < 406){ nt_local = tile - 404; s = oW1; Nsrc = 23; }
  else                { nt_local = tile - 406; s = oW2; Nsrc = 20; }

  int n = nt_local * 16 + (lane & 15);
  int k = kc * 32 + ((lane >> 4) << 3);
  bf16x8 bv;
  if (n < Nsrc){
    const float* sp = s + (size_t)n * 256 + k;
    #pragma unroll
    for (int i = 0; i < 8; ++i) bv[i] = (short)f2bf(sp[i]);
  } else {
    #pragma unroll
    for (int i = 0; i < 8; ++i) bv[i] = 0;
  }
  *(bf16x8*)(pk + (size_t)g * 8) = bv;
}

// ---------------------------------------------------------------------------
// GEMM helpers (R11 layout). A: LDS [32 rows][256 k] bf16, XOR-swizzled
// ((row&7)<<3). B: packed frags. Lane holds D[(l>>4)*4+r][l&15].
// ---------------------------------------------------------------------------

// fused dual-source 4-gate pass: acc += x*Wih^T + h*Whh^T (per gate)
__device__ __forceinline__ void gate_gemm_dual(const unsigned short* sAx,
                                               const unsigned short* sAh,
                                               const unsigned short* pkBx,
                                               const unsigned short* pkBh,
                                               int nt0, int lane, f32x4 (&acc)[2][4])
{
  const bf16x8* Bx = (const bf16x8*)pkBx;
  const bf16x8* Bh = (const bf16x8*)pkBh;
  const int g16  = (lane >> 4) << 3;
  const int swz  = (lane & 7) << 3;
  const int rbase = lane & 15;
  __builtin_amdgcn_s_setprio(2);
  #pragma unroll
  for (int kc = 0; kc < 8; ++kc){
    bf16x8 bx0 = Bx[(nt0     ) * 512 + kc * 64 + lane];
    bf16x8 bx1 = Bx[(nt0 + 16) * 512 + kc * 64 + lane];
    bf16x8 bx2 = Bx[(nt0 + 32) * 512 + kc * 64 + lane];
    bf16x8 bx3 = Bx[(nt0 + 48) * 512 + kc * 64 + lane];
    bf16x8 bh0 = Bh[(nt0     ) * 512 + kc * 64 + lane];
    bf16x8 bh1 = Bh[(nt0 + 16) * 512 + kc * 64 + lane];
    bf16x8 bh2 = Bh[(nt0 + 32) * 512 + kc * 64 + lane];
    bf16x8 bh3 = Bh[(nt0 + 48) * 512 + kc * 64 + lane];
    int kcol = (kc * 32 + g16) ^ swz;
    #pragma unroll
    for (int mt = 0; mt < 2; ++mt){
      bf16x8 ax = *(const bf16x8*)(sAx + (mt * 16 + rbase) * 256 + kcol);
      bf16x8 ah = *(const bf16x8*)(sAh + (mt * 16 + rbase) * 256 + kcol);
      acc[mt][0] = __builtin_amdgcn_mfma_f32_16x16x32_bf16(ax, bx0, acc[mt][0], 0, 0, 0);
      acc[mt][1] = __builtin_amdgcn_mfma_f32_16x16x32_bf16(ax, bx1, acc[mt][1], 0, 0, 0);
      acc[mt][2] = __builtin_amdgcn_mfma_f32_16x16x32_bf16(ax, bx2, acc[mt][2], 0, 0, 0);
      acc[mt][3] = __builtin_amdgcn_mfma_f32_16x16x32_bf16(ax, bx3, acc[mt][3], 0, 0, 0);
      acc[mt][0] = __builtin_amdgcn_mfma_f32_16x16x32_bf16(ah, bh0, acc[mt][0], 0, 0, 0);
      acc[mt][1] = __builtin_amdgcn_mfma_f32_16x16x32_bf16(ah, bh1, acc[mt][1], 0, 0, 0);
      acc[mt][2] = __builtin_amdgcn_mfma_f32_16x16x32_bf16(ah, bh2, acc[mt][2], 0, 0, 0);
      acc[mt][3] = __builtin_amdgcn_mfma_f32_16x16x32_bf16(ah, bh3, acc[mt][3], 0, 0, 0);
    }
  }
  __builtin_amdgcn_s_setprio(0);
}

// stage-0 variant: f-gate dead (c=0) -> only i,g,o
__device__ __forceinline__ void gate_gemm3(const unsigned short* sA, const unsigned short* pkB,
                                           int nt0, int lane, f32x4 (&acc)[2][3])
{
  const bf16x8* B = (const bf16x8*)pkB;
  const int g16  = (lane >> 4) << 3;
  const int swz  = (lane & 7) << 3;
  const int rbase = lane & 15;
  __builtin_amdgcn_s_setprio(2);
  #pragma unroll
  for (int kc = 0; kc < 8; ++kc){
    bf16x8 b0 = B[(nt0     ) * 512 + kc * 64 + lane];
    bf16x8 b2 = B[(nt0 + 32) * 512 + kc * 64 + lane];
    bf16x8 b3 = B[(nt0 + 48) * 512 + kc * 64 + lane];
    int kcol = (kc * 32 + g16) ^ swz;
    #pragma unroll
    for (int mt = 0; mt < 2; ++mt){
      bf16x8 a = *(const bf16x8*)(sA + (mt * 16 + rbase) * 256 + kcol);
      acc[mt][0] = __builtin_amdgcn_mfma_f32_16x16x32_bf16(a, b0, acc[mt][0], 0, 0, 0);
      acc[mt][1] = __builtin_amdgcn_mfma_f32_16x16x32_bf16(a, b2, acc[mt][1], 0, 0, 0);
      acc[mt][2] = __builtin_amdgcn_mfma_f32_16x16x32_bf16(a, b3, acc[mt][2], 0, 0, 0);
    }
  }
  __builtin_amdgcn_s_setprio(0);
}

__device__ __forceinline__ void gemm1(const unsigned short* sA, const unsigned short* pkB,
                                      int nt, int lane, f32x4 (&acc)[2])
{
  const bf16x8* B = (const bf16x8*)pkB;
  const int g16  = (lane >> 4) << 3;
  const int swz  = (lane & 7) << 3;
  const int rbase = lane & 15;
  __builtin_amdgcn_s_setprio(1);
  #pragma unroll
  for (int kc = 0; kc < 8; ++kc){
    bf16x8 b = B[nt * 512 + kc * 64 + lane];
    int kcol = (kc * 32 + g16) ^ swz;
    #pragma unroll
    for (int mt = 0; mt < 2; ++mt){
      bf16x8 a = *(const bf16x8*)(sA + (mt * 16 + rbase) * 256 + kcol);
      acc[mt] = __builtin_amdgcn_mfma_f32_16x16x32_bf16(a, b, acc[mt], 0, 0, 0);
    }
  }
  __builtin_amdgcn_s_setprio(0);
}

// single 16-row block at row base mh*16 for the tiny out GEMMs
__device__ __forceinline__ void gemm1q(const unsigned short* sA, const unsigned short* pkB,
                                       int nt, int mh, int lane, f32x4 &acc)
{
  const bf16x8* B = (const bf16x8*)pkB;
  const int g16  = (lane >> 4) << 3;
  const int swz  = (lane & 7) << 3;
  const int rbase = mh * 16 + (lane & 15);
  __builtin_amdgcn_s_setprio(1);
  #pragma unroll
  for (int kc = 0; kc < 8; ++kc){
    bf16x8 b = B[nt * 512 + kc * 64 + lane];
    int kcol = (kc * 32 + g16) ^ swz;
    bf16x8 a = *(const bf16x8*)(sA + rbase * 256 + kcol);
    acc = __builtin_amdgcn_mfma_f32_16x16x32_bf16(a, b, acc, 0, 0, 0);
  }
  __builtin_amdgcn_s_setprio(0);
}

// ---------------------------------------------------------------------------
// (256,2): VGPR cap 128 -> 2 waves/SIMD; 64 KiB LDS -> 2 WG/CU, indep clocks.
__global__ __launch_bounds__(256, 2)
void lstm_fused(const float* __restrict__ x, const unsigned short* __restrict__ pk,
                const float* __restrict__ bih, const float* __restrict__ bhh,
                const float* __restrict__ hsb, const float* __restrict__ csb,
                const float* __restrict__ midb,
                const float* __restrict__ ob0, const float* __restrict__ ob1,
                const float* __restrict__ ob2, float* __restrict__ out)
{
  __shared__ __align__(16) unsigned short smem[32768];   // 64 KiB
  unsigned short* s_x  = smem;            // x (bf16)  [32][256]
  unsigned short* s_h0 = smem + 8192;     // h0, then hh
  unsigned short* s_h1 = smem + 16384;    // h1, then h2
  unsigned short* s_bu = smem + 24576;    // mid / c1

  const int tid  = threadIdx.x;
  const int lane = tid & 63;
  const int w    = tid >> 6;              // col quarter 0..3
  const int row0 = blockIdx.x * 32;
  const int rsub = (lane >> 4) << 2;
  const int jl   = lane & 15;

  // ---- stage x into LDS (f32 -> bf16, swizzled)
  {
    const float* xg = x + (size_t)row0 * 256;
    #pragma unroll
    for (int it = 0; it < 4; ++it){
      int idx = it * 2048 + tid * 8;
      int row = idx >> 8, col = idx & 255;
      float4 v0 = *(const float4*)(xg + idx);
      float4 v1 = *(const float4*)(xg + idx + 4);
      bf16x8 bv;
      bv[0]=(short)f2bf(v0.x); bv[1]=(short)f2bf(v0.y); bv[2]=(short)f2bf(v0.z); bv[3]=(short)f2bf(v0.w);
      bv[4]=(short)f2bf(v1.x); bv[5]=(short)f2bf(v1.y); bv[6]=(short)f2bf(v1.z); bv[7]=(short)f2bf(v1.w);
      *(bf16x8*)(s_x + row * 256 + (col ^ ((row & 7) << 3))) = bv;
    }
  }
  __syncthreads();

  float c0[4][2][4];   // c-state in regs: [t][mt][r]

  // ======== STAGE 0: gates from x only (h=c=0); f-gate skipped
  #pragma unroll
  for (int t = 0; t < 4; ++t){
    int jb = w * 64 + t * 16, nt0 = w * 4 + t, j = jb + jl;
    f32x4 acc[2][3] = {};
    gate_gemm3(s_x, pk + OFF_WIH, nt0, lane, acc);
    float bi = bih[j]       + bhh[j];
    float bg = bih[512 + j] + bhh[512 + j];
    float bo = bih[768 + j] + bhh[768 + j];
    #pragma unroll
    for (int mt = 0; mt < 2; ++mt){
      #pragma unroll
      for (int r = 0; r < 4; ++r){
        float c = sigm(acc[mt][0][r] + bi) * tanh_(acc[mt][1][r] + bg);
        float h = sigm(acc[mt][2][r] + bo) * tanh_(c);
        c0[t][mt][r] = c;
        int m = mt * 16 + rsub + r;
        s_h0[m * 256 + (j ^ ((m & 7) << 3))] = f2bf(h);
      }
    }
  }
  __syncthreads();

  // ======== MID0
  #pragma unroll
  for (int t = 0; t < 4; ++t){
    int jb = w * 64 + t * 16, j = jb + jl;
    f32x4 am[2] = {};
    gemm1(s_h0, pk + OFF_MID, w * 4 + t, lane, am);
    float mb = midb[j];
    #pragma unroll
    for (int mt = 0; mt < 2; ++mt){
      #pragma unroll
      for (int r = 0; r < 4; ++r){
        float mv = am[mt][r] + mb; mv = mv > 0.f ? mv : 0.f;
        int m = mt * 16 + rsub + r;
        s_bu[m * 256 + (j ^ ((m & 7) << 3))] = f2bf(mv);
      }
    }
  }
  __syncthreads();

  // ======== OUT0 (54 cols): wave w -> nt=w, rows 0..31; direct global store
  {
    f32x4 ao[2] = {};
    gemm1(s_bu, pk + OFF_OUT0, w, lane, ao);
    int colc = w * 16 + jl;
    if (colc < 54){
      float ob = ob0[colc];
      #pragma unroll
      for (int mt = 0; mt < 2; ++mt)
        #pragma unroll
        for (int r = 0; r < 4; ++r){
          int m = mt * 16 + rsub + r;
          out[(size_t)(row0 + m) * 54 + colc] = ao[mt][r] + ob;
        }
    }
  }
  __syncthreads();   // s_bu reads done before stage1 writes c1

  // ======== STAGE 1: fused dual-source gates; uses c0
  #pragma unroll
  for (int t = 0; t < 4; ++t){
    int jb = w * 64 + t * 16, nt0 = w * 4 + t, j = jb + jl;
    f32x4 acc[2][4] = {};
    gate_gemm_dual(s_x, s_h0, pk + OFF_WIH + 262144, pk + OFF_WHH, nt0, lane, acc);
    float bi = bih[1024 + j]       + bhh[1024 + j];
    float bf_= bih[1024 + 256 + j] + bhh[1024 + 256 + j];
    float bg = bih[1024 + 512 + j] + bhh[1024 + 512 + j];
    float bo = bih[1024 + 768 + j] + bhh[1024 + 768 + j];
    #pragma unroll
    for (int mt = 0; mt < 2; ++mt){
      #pragma unroll
      for (int r = 0; r < 4; ++r){
        float c1 = sigm(acc[mt][1][r] + bf_) * c0[t][mt][r]
                 + sigm(acc[mt][0][r] + bi ) * tanh_(acc[mt][2][r] + bg);
        float h1 = sigm(acc[mt][3][r] + bo) * tanh_(c1);
        int m = mt * 16 + rsub + r;
        int ofs = m * 256 + (j ^ ((m & 7) << 3));
        s_h1[ofs] = f2bf(h1);
        s_bu[ofs] = f2bf(c1);
      }
    }
  }
  __syncthreads();

  // ======== HS/CS mix: hh = h0 + h1*hsW^T + hsb (in place); cc into c0 regs
  #pragma unroll
  for (int t = 0; t < 4; ++t){
    int jb = w * 64 + t * 16, nt = w * 4 + t, j = jb + jl;
    f32x4 ah[2] = {}, ac[2] = {};
    gemm1(s_h1, pk + OFF_HS, nt, lane, ah);
    gemm1(s_bu, pk + OFF_CS, nt, lane, ac);
    float hb = hsb[j], cb = csb[j];
    #pragma unroll
    for (int mt = 0; mt < 2; ++mt){
      #pragma unroll
      for (int r = 0; r < 4; ++r){
        int m = mt * 16 + rsub + r;
        int ofs = m * 256 + (j ^ ((m & 7) << 3));
        float hh = bf2f(s_h0[ofs]) + ah[mt][r] + hb;   // own slot: no race
        s_h0[ofs] = f2bf(hh);
        c0[t][mt][r] += ac[mt][r] + cb;
      }
    }
  }
  __syncthreads();

  // ======== MID1
  #pragma unroll
  for (int t = 0; t < 4; ++t){
    int jb = w * 64 + t * 16, j = jb + jl;
    f32x4 am[2] = {};
    gemm1(s_h1, pk + OFF_MID + 65536, w * 4 + t, lane, am);
    float mb = midb[256 + j];
    #pragma unroll
    for (int mt = 0; mt < 2; ++mt){
      #pragma unroll
      for (int r = 0; r < 4; ++r){
        float mv = am[mt][r] + mb; mv = mv > 0.f ? mv : 0.f;
        int m = mt * 16 + rsub + r;
        s_bu[m * 256 + (j ^ ((m & 7) << 3))] = f2bf(mv);
      }
    }
  }
  __syncthreads();

  // ======== OUT1 (23 cols): direct store; NO barrier after (stage2 touches
  // only s_x/s_h0/s_h1; next s_bu writer MID2 is behind stage2's barrier)
  {
    f32x4 ao = {0.f, 0.f, 0.f, 0.f};
    gemm1q(s_bu, pk + OFF_OUT1, w & 1, w >> 1, lane, ao);
    int colc = (w & 1) * 16 + jl;
    if (colc < 23){
      float ob = ob1[colc];
      #pragma unroll
      for (int r = 0; r < 4; ++r){
        int m = (w >> 1) * 16 + rsub + r;
        out[3538944 + (size_t)(row0 + m) * 23 + colc] = ao[r] + ob;
      }
    }
  }

  // ======== STAGE 2: fused dual-source gates; uses cc (in c0)
  #pragma unroll
  for (int t = 0; t < 4; ++t){
    int jb = w * 64 + t * 16, nt0 = w * 4 + t, j = jb + jl;
    f32x4 acc[2][4] = {};
    gate_gemm_dual(s_x, s_h0, pk + OFF_WIH + 524288, pk + OFF_WHH + 262144, nt0, lane, acc);
    float bi = bih[2048 + j]       + bhh[2048 + j];
    float bf_= bih[2048 + 256 + j] + bhh[2048 + 256 + j];
    float bg = bih[2048 + 512 + j] + bhh[2048 + 512 + j];
    float bo = bih[2048 + 768 + j] + bhh[2048 + 768 + j];
    #pragma unroll
    for (int mt = 0; mt < 2; ++mt){
      #pragma unroll
      for (int r = 0; r < 4; ++r){
        float c2 = sigm(acc[mt][1][r] + bf_) * c0[t][mt][r]
                 + sigm(acc[mt][0][r] + bi ) * tanh_(acc[mt][2][r] + bg);
        float h2 = sigm(acc[mt][3][r] + bo) * tanh_(c2);
        int m = mt * 16 + rsub + r;
        s_h1[m * 256 + (j ^ ((m & 7) << 3))] = f2bf(h2);
      }
    }
  }
  __syncthreads();

  // ======== MID2
  #pragma unroll
  for (int t = 0; t < 4; ++t){
    int jb = w * 64 + t * 16, j = jb + jl;
    f32x4 am[2] = {};
    gemm1(s_h1, pk + OFF_MID + 131072, w * 4 + t, lane, am);
    float mb = midb[512 + j];
    #pragma unroll
    for (int mt = 0; mt < 2; ++mt){
      #pragma unroll
      for (int r = 0; r < 4; ++r){
        float mv = am[mt][r] + mb; mv = mv > 0.f ? mv : 0.f;
        int m = mt * 16 + rsub + r;
        s_bu[m * 256 + (j ^ ((m & 7) << 3))] = f2bf(mv);
      }
    }
  }
  __syncthreads();

  // ======== OUT2 (20 cols): direct store; kernel ends
  {
    f32x4 ao = {0.f, 0.f, 0.f, 0.f};
    gemm1q(s_bu, pk + OFF_OUT2, w & 1, w >> 1, lane, ao);
    int colc = (w & 1) * 16 + jl;
    if (colc < 20){
      float ob = ob2[colc];
      #pragma unroll
      for (int r = 0; r < 4; ++r){
        int m = (w >> 1) * 16 + rsub + r;
        out[5046272 + (size_t)(row0 + m) * 20 + colc] = ao[r] + ob;
      }
    }
  }
}

extern "C" void kernel_launch(void* const* d_in, const int* in_sizes, int n_in,
                              void* d_out, int out_size, void* d_ws, size_t ws_size,
                              hipStream_t stream)
{
  const float* x     = (const float*)d_in[0];
  const float* Wih   = (const float*)d_in[1];
  const float* Whh   = (const float*)d_in[2];
  const float* bih   = (const float*)d_in[3];
  const float* bhh   = (const float*)d_in[4];
  const float* hsW   = (const float*)d_in[5];
  const float* hsb   = (const float*)d_in[6];
  const float* csW   = (const float*)d_in[7];
  const float* csb   = (const float*)d_in[8];
  const float* midW  = (const float*)d_in[9];
  const float* midb  = (const float*)d_in[10];
  const float* outW0 = (const float*)d_in[11];
  const float* outb0 = (const float*)d_in[12];
  const float* outW1 = (const float*)d_in[13];
  const float* outb1 = (const float*)d_in[14];
  const float* outW2 = (const float*)d_in[15];
  const float* outb2 = (const float*)d_in[16];

  unsigned short* pk = (unsigned short*)d_ws;

  int ngroups = PK_TOTAL / 8;
  pack_all<<<(ngroups + 255) / 256, 256, 0, stream>>>(
      Wih, Whh, hsW + 5 * 65536, csW + 5 * 65536, midW, outW0, outW1, outW2, pk);

  lstm_fused<<<2048, 256, 0, stream>>>(
      x, pk, bih, bhh, hsb + 5 * 256, csb + 5 * 256, midb,
      outb0, outb1, outb2, (float*)d_out);
}

// Round 22
// 277.245 us; speedup vs baseline: 1.4321x; 1.4321x over previous
//
#include <hip/hip_runtime.h>
#include <stdint.h>

// ============================================================================
// LSTMDecoder fused — MI355X/gfx950 — R22 (FINAL): R20 restored
//
// Frontier config (277us, absmax 1.95e-3): R11 layout (32 rows/WG, 2048 WGs,
// 256 thr, (256,2) -> 128-VGPR cap -> 2 waves/SIMD, 64 KiB LDS -> 2 indep
// WGs/CU) + T5 setprio on all GEMM passes (+30%: arbitration between the two
// WGs' phases) + direct-global OUT epilogues. Constraint surface closed:
// occupancy up -> spill (R7/R12/R13); MLP up -> spill (R21); B-sharing ->
// lockstep kills setprio (R19); VALU/conflict/barrier cuts off critical path
// (R15/R17/R18).
// ============================================================================

typedef __attribute__((ext_vector_type(8))) short bf16x8;
typedef __attribute__((ext_vector_type(4))) float f32x4;

#define OFF_WIH  0
#define OFF_WHH  786432
#define OFF_HS   1310720
#define OFF_CS   1376256
#define OFF_MID  1441792
#define OFF_OUT0 1638400
#define OFF_OUT1 1654784
#define OFF_OUT2 1662976
#define PK_TOTAL 1671168

__device__ __forceinline__ unsigned short f2bf(float f){
  uint32_t u = __float_as_uint(f);
  u += 0x7FFFu + ((u >> 16) & 1u);
  return (unsigned short)(u >> 16);
}
__device__ __forceinline__ float bf2f(unsigned short h){
  return __uint_as_float(((uint32_t)h) << 16);
}
__device__ __forceinline__ float sigm(float x){
  return __builtin_amdgcn_rcpf(1.0f + __expf(-x));
}
__device__ __forceinline__ float tanh_(float x){
  return 2.0f * __builtin_amdgcn_rcpf(1.0f + __expf(-2.0f * x)) - 1.0f;
}

// ---------------------------------------------------------------------------
__global__ __launch_bounds__(256)
void pack_all(const float* __restrict__ Wih, const float* __restrict__ Whh,
              const float* __restrict__ hsW, const float* __restrict__ csW,
              const float* __restrict__ midW,
              const float* __restrict__ oW0, const float* __restrict__ oW1,
              const float* __restrict__ oW2,
              unsigned short* __restrict__ pk)
{
  int g = blockIdx.x * 256 + threadIdx.x;
  if (g >= PK_TOTAL / 8) return;
  int tile = g >> 9;
  int within = g & 511;
  int lane = within & 63;
  int kc = within >> 6;

  const float* s; int nt_local, Nsrc;
  if      (tile < 192){ int a = tile / 64; nt_local = tile % 64; s = Wih + (size_t)a * 262144; Nsrc = 1024; }
  else if (tile < 320){ int a = 1 + (tile - 192) / 64; nt_local = (tile - 192) % 64; s = Whh + (size_t)a * 262144; Nsrc = 1024; }
  else if (tile < 336){ nt_local = tile - 320; s = hsW; Nsrc = 256; }
  else if (tile < 352){ nt_local = tile - 336; s = csW; Nsrc = 256; }
  else if (tile < 400){ int a = (tile - 352) / 16; nt_local = (tile - 352) % 16; s = midW + a * 65536; Nsrc = 256; }
  else if (tile < 404){ nt_local = tile - 400; s = oW0; Nsrc = 54; }
  else if (tile < 406){ nt_local = tile - 404; s = oW1; Nsrc = 23; }
  else                { nt_local = tile - 406; s = oW2; Nsrc = 20; }

  int n = nt_local * 16 + (lane & 15);
  int k = kc * 32 + ((lane >> 4) << 3);
  bf16x8 bv;
  if (n < Nsrc){
    const float* sp = s + (size_t)n * 256 + k;
    #pragma unroll
    for (int i = 0; i < 8; ++i) bv[i] = (short)f2bf(sp[i]);
  } else {
    #pragma unroll
    for (int i = 0; i < 8; ++i) bv[i] = 0;
  }
  *(bf16x8*)(pk + (size_t)g * 8) = bv;
}

// ---------------------------------------------------------------------------
// GEMM helpers (R11 layout). A: LDS [32 rows][256 k] bf16, XOR-swizzled
// ((row&7)<<3). B: packed frags. Lane holds D[(l>>4)*4+r][l&15].
// Gate passes: setprio(2); small passes: setprio(1).
// ---------------------------------------------------------------------------
__device__ __forceinline__ void gate_gemm(const unsigned short* sA, const unsigned short* pkB,
                                          int nt0, int lane, f32x4 (&acc)[2][4])
{
  const bf16x8* B = (const bf16x8*)pkB;
  const int g16  = (lane >> 4) << 3;
  const int swz  = (lane & 7) << 3;
  const int rbase = lane & 15;
  __builtin_amdgcn_s_setprio(2);
  #pragma unroll
  for (int kc = 0; kc < 8; ++kc){
    bf16x8 b0 = B[(nt0     ) * 512 + kc * 64 + lane];
    bf16x8 b1 = B[(nt0 + 16) * 512 + kc * 64 + lane];
    bf16x8 b2 = B[(nt0 + 32) * 512 + kc * 64 + lane];
    bf16x8 b3 = B[(nt0 + 48) * 512 + kc * 64 + lane];
    int kcol = (kc * 32 + g16) ^ swz;
    #pragma unroll
    for (int mt = 0; mt < 2; ++mt){
      bf16x8 a = *(const bf16x8*)(sA + (mt * 16 + rbase) * 256 + kcol);
      acc[mt][0] = __builtin_amdgcn_mfma_f32_16x16x32_bf16(a, b0, acc[mt][0], 0, 0, 0);
      acc[mt][1] = __builtin_amdgcn_mfma_f32_16x16x32_bf16(a, b1, acc[mt][1], 0, 0, 0);
      acc[mt][2] = __builtin_amdgcn_mfma_f32_16x16x32_bf16(a, b2, acc[mt][2], 0, 0, 0);
      acc[mt][3] = __builtin_amdgcn_mfma_f32_16x16x32_bf16(a, b3, acc[mt][3], 0, 0, 0);
    }
  }
  __builtin_amdgcn_s_setprio(0);
}

// stage-0 variant: f-gate dead (c=0) -> only i,g,o
__device__ __forceinline__ void gate_gemm3(const unsigned short* sA, const unsigned short* pkB,
                                           int nt0, int lane, f32x4 (&acc)[2][3])
{
  const bf16x8* B = (const bf16x8*)pkB;
  const int g16  = (lane >> 4) << 3;
  const int swz  = (lane & 7) << 3;
  const int rbase = lane & 15;
  __builtin_amdgcn_s_setprio(2);
  #pragma unroll
  for (int kc = 0; kc < 8; ++kc){
    bf16x8 b0 = B[(nt0     ) * 512 + kc * 64 + lane];
    bf16x8 b2 = B[(nt0 + 32) * 512 + kc * 64 + lane];
    bf16x8 b3 = B[(nt0 + 48) * 512 + kc * 64 + lane];
    int kcol = (kc * 32 + g16) ^ swz;
    #pragma unroll
    for (int mt = 0; mt < 2; ++mt){
      bf16x8 a = *(const bf16x8*)(sA + (mt * 16 + rbase) * 256 + kcol);
      acc[mt][0] = __builtin_amdgcn_mfma_f32_16x16x32_bf16(a, b0, acc[mt][0], 0, 0, 0);
      acc[mt][1] = __builtin_amdgcn_mfma_f32_16x16x32_bf16(a, b2, acc[mt][1], 0, 0, 0);
      acc[mt][2] = __builtin_amdgcn_mfma_f32_16x16x32_bf16(a, b3, acc[mt][2], 0, 0, 0);
    }
  }
  __builtin_amdgcn_s_setprio(0);
}

__device__ __forceinline__ void gemm1(const unsigned short* sA, const unsigned short* pkB,
                                      int nt, int lane, f32x4 (&acc)[2])
{
  const bf16x8* B = (const bf16x8*)pkB;
  const int g16  = (lane >> 4) << 3;
  const int swz  = (lane & 7) << 3;
  const int rbase = lane & 15;
  __builtin_amdgcn_s_setprio(1);
  #pragma unroll
  for (int kc = 0; kc < 8; ++kc){
    bf16x8 b = B[nt * 512 + kc * 64 + lane];
    int kcol = (kc * 32 + g16) ^ swz;
    #pragma unroll
    for (int mt = 0; mt < 2; ++mt){
      bf16x8 a = *(const bf16x8*)(sA + (mt * 16 + rbase) * 256 + kcol);
      acc[mt] = __builtin_amdgcn_mfma_f32_16x16x32_bf16(a, b, acc[mt], 0, 0, 0);
    }
  }
  __builtin_amdgcn_s_setprio(0);
}

// single 16-row block at row base mh*16 for the tiny out GEMMs
__device__ __forceinline__ void gemm1q(const unsigned short* sA, const unsigned short* pkB,
                                       int nt, int mh, int lane, f32x4 &acc)
{
  const bf16x8* B = (const bf16x8*)pkB;
  const int g16  = (lane >> 4) << 3;
  const int swz  = (lane & 7) << 3;
  const int rbase = mh * 16 + (lane & 15);
  __builtin_amdgcn_s_setprio(1);
  #pragma unroll
  for (int kc = 0; kc < 8; ++kc){
    bf16x8 b = B[nt * 512 + kc * 64 + lane];
    int kcol = (kc * 32 + g16) ^ swz;
    bf16x8 a = *(const bf16x8*)(sA + rbase * 256 + kcol);
    acc = __builtin_amdgcn_mfma_f32_16x16x32_bf16(a, b, acc, 0, 0, 0);
  }
  __builtin_amdgcn_s_setprio(0);
}

// ---------------------------------------------------------------------------
// (256,2): VGPR cap 128 -> 2 waves/SIMD; 64 KiB LDS -> 2 WG/CU, indep clocks.
__global__ __launch_bounds__(256, 2)
void lstm_fused(const float* __restrict__ x, const unsigned short* __restrict__ pk,
                const float* __restrict__ bih, const float* __restrict__ bhh,
                const float* __restrict__ hsb, const float* __restrict__ csb,
                const float* __restrict__ midb,
                const float* __restrict__ ob0, const float* __restrict__ ob1,
                const float* __restrict__ ob2, float* __restrict__ out)
{
  __shared__ __align__(16) unsigned short smem[32768];   // 64 KiB
  unsigned short* s_x  = smem;            // x (bf16)  [32][256]
  unsigned short* s_h0 = smem + 8192;     // h0, then hh
  unsigned short* s_h1 = smem + 16384;    // h1, then h2
  unsigned short* s_bu = smem + 24576;    // mid / c1

  const int tid  = threadIdx.x;
  const int lane = tid & 63;
  const int w    = tid >> 6;              // col quarter 0..3
  const int row0 = blockIdx.x * 32;
  const int rsub = (lane >> 4) << 2;
  const int jl   = lane & 15;

  // ---- stage x into LDS (f32 -> bf16, swizzled)
  {
    const float* xg = x + (size_t)row0 * 256;
    #pragma unroll
    for (int it = 0; it < 4; ++it){
      int idx = it * 2048 + tid * 8;
      int row = idx >> 8, col = idx & 255;
      float4 v0 = *(const float4*)(xg + idx);
      float4 v1 = *(const float4*)(xg + idx + 4);
      bf16x8 bv;
      bv[0]=(short)f2bf(v0.x); bv[1]=(short)f2bf(v0.y); bv[2]=(short)f2bf(v0.z); bv[3]=(short)f2bf(v0.w);
      bv[4]=(short)f2bf(v1.x); bv[5]=(short)f2bf(v1.y); bv[6]=(short)f2bf(v1.z); bv[7]=(short)f2bf(v1.w);
      *(bf16x8*)(s_x + row * 256 + (col ^ ((row & 7) << 3))) = bv;
    }
  }
  __syncthreads();

  float c0[4][2][4];   // c-state in regs: [t][mt][r]

  // ======== STAGE 0: gates from x only (h=c=0); f-gate skipped
  #pragma unroll
  for (int t = 0; t < 4; ++t){
    int jb = w * 64 + t * 16, nt0 = w * 4 + t, j = jb + jl;
    f32x4 acc[2][3] = {};
    gate_gemm3(s_x, pk + OFF_WIH, nt0, lane, acc);
    float bi = bih[j]       + bhh[j];
    float bg = bih[512 + j] + bhh[512 + j];
    float bo = bih[768 + j] + bhh[768 + j];
    #pragma unroll
    for (int mt = 0; mt < 2; ++mt){
      #pragma unroll
      for (int r = 0; r < 4; ++r){
        float c = sigm(acc[mt][0][r] + bi) * tanh_(acc[mt][1][r] + bg);
        float h = sigm(acc[mt][2][r] + bo) * tanh_(c);
        c0[t][mt][r] = c;
        int m = mt * 16 + rsub + r;
        s_h0[m * 256 + (j ^ ((m & 7) << 3))] = f2bf(h);
      }
    }
  }
  __syncthreads();

  // ======== MID0
  #pragma unroll
  for (int t = 0; t < 4; ++t){
    int jb = w * 64 + t * 16, j = jb + jl;
    f32x4 am[2] = {};
    gemm1(s_h0, pk + OFF_MID, w * 4 + t, lane, am);
    float mb = midb[j];
    #pragma unroll
    for (int mt = 0; mt < 2; ++mt){
      #pragma unroll
      for (int r = 0; r < 4; ++r){
        float mv = am[mt][r] + mb; mv = mv > 0.f ? mv : 0.f;
        int m = mt * 16 + rsub + r;
        s_bu[m * 256 + (j ^ ((m & 7) << 3))] = f2bf(mv);
      }
    }
  }
  __syncthreads();

  // ======== OUT0 (54 cols): wave w -> nt=w, rows 0..31; direct global store
  {
    f32x4 ao[2] = {};
    gemm1(s_bu, pk + OFF_OUT0, w, lane, ao);
    int colc = w * 16 + jl;
    if (colc < 54){
      float ob = ob0[colc];
      #pragma unroll
      for (int mt = 0; mt < 2; ++mt)
        #pragma unroll
        for (int r = 0; r < 4; ++r){
          int m = mt * 16 + rsub + r;
          out[(size_t)(row0 + m) * 54 + colc] = ao[mt][r] + ob;
        }
    }
  }
  __syncthreads();   // s_bu reads done before stage1 writes c1

  // ======== STAGE 1: gates from x and h0; uses c0
  #pragma unroll
  for (int t = 0; t < 4; ++t){
    int jb = w * 64 + t * 16, nt0 = w * 4 + t, j = jb + jl;
    f32x4 acc[2][4] = {};
    gate_gemm(s_x,  pk + OFF_WIH + 262144, nt0, lane, acc);
    gate_gemm(s_h0, pk + OFF_WHH,          nt0, lane, acc);
    float bi = bih[1024 + j]       + bhh[1024 + j];
    float bf_= bih[1024 + 256 + j] + bhh[1024 + 256 + j];
    float bg = bih[1024 + 512 + j] + bhh[1024 + 512 + j];
    float bo = bih[1024 + 768 + j] + bhh[1024 + 768 + j];
    #pragma unroll
    for (int mt = 0; mt < 2; ++mt){
      #pragma unroll
      for (int r = 0; r < 4; ++r){
        float c1 = sigm(acc[mt][1][r] + bf_) * c0[t][mt][r]
                 + sigm(acc[mt][0][r] + bi ) * tanh_(acc[mt][2][r] + bg);
        float h1 = sigm(acc[mt][3][r] + bo) * tanh_(c1);
        int m = mt * 16 + rsub + r;
        int ofs = m * 256 + (j ^ ((m & 7) << 3));
        s_h1[ofs] = f2bf(h1);
        s_bu[ofs] = f2bf(c1);
      }
    }
  }
  __syncthreads();

  // ======== HS/CS mix: hh = h0 + h1*hsW^T + hsb (in place); cc into c0 regs
  #pragma unroll
  for (int t = 0; t < 4; ++t){
    int jb = w * 64 + t * 16, nt = w * 4 + t, j = jb + jl;
    f32x4 ah[2] = {}, ac[2] = {};
    gemm1(s_h1, pk + OFF_HS, nt, lane, ah);
    gemm1(s_bu, pk + OFF_CS, nt, lane, ac);
    float hb = hsb[j], cb = csb[j];
    #pragma unroll
    for (int mt = 0; mt < 2; ++mt){
      #pragma unroll
      for (int r = 0; r < 4; ++r){
        int m = mt * 16 + rsub + r;
        int ofs = m * 256 + (j ^ ((m & 7) << 3));
        float hh = bf2f(s_h0[ofs]) + ah[mt][r] + hb;   // own slot: no race
        s_h0[ofs] = f2bf(hh);
        c0[t][mt][r] += ac[mt][r] + cb;
      }
    }
  }
  __syncthreads();

  // ======== MID1
  #pragma unroll
  for (int t = 0; t < 4; ++t){
    int jb = w * 64 + t * 16, j = jb + jl;
    f32x4 am[2] = {};
    gemm1(s_h1, pk + OFF_MID + 65536, w * 4 + t, lane, am);
    float mb = midb[256 + j];
    #pragma unroll
    for (int mt = 0; mt < 2; ++mt){
      #pragma unroll
      for (int r = 0; r < 4; ++r){
        float mv = am[mt][r] + mb; mv = mv > 0.f ? mv : 0.f;
        int m = mt * 16 + rsub + r;
        s_bu[m * 256 + (j ^ ((m & 7) << 3))] = f2bf(mv);
      }
    }
  }
  __syncthreads();

  // ======== OUT1 (23 cols): direct store; NO barrier after (stage2 touches
  // only s_x/s_h0/s_h1; next s_bu writer MID2 is behind stage2's barrier)
  {
    f32x4 ao = {0.f, 0.f, 0.f, 0.f};
    gemm1q(s_bu, pk + OFF_OUT1, w & 1, w >> 1, lane, ao);
    int colc = (w & 1) * 16 + jl;
    if (colc < 23){
      float ob = ob1[colc];
      #pragma unroll
      for (int r = 0; r < 4; ++r){
        int m = (w >> 1) * 16 + rsub + r;
        out[3538944 + (size_t)(row0 + m) * 23 + colc] = ao[r] + ob;
      }
    }
  }

  // ======== STAGE 2: gates from x and hh; uses cc (in c0)
  #pragma unroll
  for (int t = 0; t < 4; ++t){
    int jb = w * 64 + t * 16, nt0 = w * 4 + t, j = jb + jl;
    f32x4 acc[2][4] = {};
    gate_gemm(s_x,  pk + OFF_WIH + 524288, nt0, lane, acc);
    gate_gemm(s_h0, pk + OFF_WHH + 262144, nt0, lane, acc);
    float bi = bih[2048 + j]       + bhh[2048 + j];
    float bf_= bih[2048 + 256 + j] + bhh[2048 + 256 + j];
    float bg = bih[2048 + 512 + j] + bhh[2048 + 512 + j];
    float bo = bih[2048 + 768 + j] + bhh[2048 + 768 + j];
    #pragma unroll
    for (int mt = 0; mt < 2; ++mt){
      #pragma unroll
      for (int r = 0; r < 4; ++r){
        float c2 = sigm(acc[mt][1][r] + bf_) * c0[t][mt][r]
                 + sigm(acc[mt][0][r] + bi ) * tanh_(acc[mt][2][r] + bg);
        float h2 = sigm(acc[mt][3][r] + bo) * tanh_(c2);
        int m = mt * 16 + rsub + r;
        s_h1[m * 256 + (j ^ ((m & 7) << 3))] = f2bf(h2);
      }
    }
  }
  __syncthreads();

  // ======== MID2
  #pragma unroll
  for (int t = 0; t < 4; ++t){
    int jb = w * 64 + t * 16, j = jb + jl;
    f32x4 am[2] = {};
    gemm1(s_h1, pk + OFF_MID + 131072, w * 4 + t, lane, am);
    float mb = midb[512 + j];
    #pragma unroll
    for (int mt = 0; mt < 2; ++mt){
      #pragma unroll
      for (int r = 0; r < 4; ++r){
        float mv = am[mt][r] + mb; mv = mv > 0.f ? mv : 0.f;
        int m = mt * 16 + rsub + r;
        s_bu[m * 256 + (j ^ ((m & 7) << 3))] = f2bf(mv);
      }
    }
  }
  __syncthreads();

  // ======== OUT2 (20 cols): direct store; kernel ends
  {
    f32x4 ao = {0.f, 0.f, 0.f, 0.f};
    gemm1q(s_bu, pk + OFF_OUT2, w & 1, w >> 1, lane, ao);
    int colc = (w & 1) * 16 + jl;
    if (colc < 20){
      float ob = ob2[colc];
      #pragma unroll
      for (int r = 0; r < 4; ++r){
        int m = (w >> 1) * 16 + rsub + r;
        out[5046272 + (size_t)(row0 + m) * 20 + colc] = ao[r] + ob;
      }
    }
  }
}

extern "C" void kernel_launch(void* const* d_in, const int* in_sizes, int n_in,
                              void* d_out, int out_size, void* d_ws, size_t ws_size,
                              hipStream_t stream)
{
  const float* x     = (const float*)d_in[0];
  const float* Wih   = (const float*)d_in[1];
  const float* Whh   = (const float*)d_in[2];
  const float* bih   = (const float*)d_in[3];
  const float* bhh   = (const float*)d_in[4];
  const float* hsW   = (const float*)d_in[5];
  const float* hsb   = (const float*)d_in[6];
  const float* csW   = (const float*)d_in[7];
  const float* csb   = (const float*)d_in[8];
  const float* midW  = (const float*)d_in[9];
  const float* midb  = (const float*)d_in[10];
  const float* outW0 = (const float*)d_in[11];
  const float* outb0 = (const float*)d_in[12];
  const float* outW1 = (const float*)d_in[13];
  const float* outb1 = (const float*)d_in[14];
  const float* outW2 = (const float*)d_in[15];
  const float* outb2 = (const float*)d_in[16];

  unsigned short* pk = (unsigned short*)d_ws;

  int ngroups = PK_TOTAL / 8;
  pack_all<<<(ngroups + 255) / 256, 256, 0, stream>>>(
      Wih, Whh, hsW + 5 * 65536, csW + 5 * 65536, midW, outW0, outW1, outW2, pk);

  lstm_fused<<<2048, 256, 0, stream>>>(
      x, pk, bih, bhh, hsb + 5 * 256, csb + 5 * 256, midb,
      outb0, outb1, outb2, (float*)d_out);
}